// Round 1
// baseline (1007.181 us; speedup 1.0000x reference)
//
#include <hip/hip_runtime.h>

// Problem: segment rows of x (sorted by index) into B=8192 sequences (cap 100),
// run single-layer LSTM (F=64, H=64) per sequence, output last hidden state.
// out: [B, 64] float32.

#define MAXLEN 100
#define HDIM 64
#define GDIM 256   // 4*HDIM gate rows

// --- Kernel A: per-segment start offset + length via binary search (index sorted) ---
__global__ void seg_bounds_kernel(const int* __restrict__ index, int N, int B,
                                  int* __restrict__ starts, int* __restrict__ lens) {
    int b = blockIdx.x * blockDim.x + threadIdx.x;
    if (b >= B) return;
    // lower_bound(index, b)
    int lo = 0, hi = N;
    while (lo < hi) { int mid = (lo + hi) >> 1; if (index[mid] < b) lo = mid + 1; else hi = mid; }
    int s = lo;
    // lower_bound(index, b+1)
    hi = N;
    while (lo < hi) { int mid = (lo + hi) >> 1; if (index[mid] < b + 1) lo = mid + 1; else hi = mid; }
    int len = lo - s;
    starts[b] = s;
    lens[b] = len < MAXLEN ? len : MAXLEN;
}

__device__ __forceinline__ float sigmoid_fast(float v) {
    return 1.0f / (1.0f + __expf(-v));
}
__device__ __forceinline__ float tanh_fast(float v) {
    return 2.0f / (1.0f + __expf(-2.0f * v)) - 1.0f;
}

// --- Kernel B: one block per segment. Thread j owns gate row j (weights in VGPRs). ---
__global__ __launch_bounds__(256, 2)
void lstm_kernel(const float* __restrict__ x,
                 const float* __restrict__ Wih,
                 const float* __restrict__ Whh,
                 const float* __restrict__ bih,
                 const float* __restrict__ bhh,
                 const int* __restrict__ starts,
                 const int* __restrict__ lens,
                 float* __restrict__ out) {
    const int tid = threadIdx.x;
    const int b = blockIdx.x;

    __shared__ __align__(16) float xbuf[2][HDIM];
    __shared__ __align__(16) float hbuf[HDIM];
    __shared__ float gbuf[GDIM];

    // Weight rows for gate-row `tid` into registers: 32 float4 = 128 VGPRs.
    float4 wih[16], whh[16];
    {
        const float4* pi = (const float4*)(Wih + (size_t)tid * HDIM);
        const float4* ph = (const float4*)(Whh + (size_t)tid * HDIM);
#pragma unroll
        for (int i = 0; i < 16; ++i) { wih[i] = pi[i]; whh[i] = ph[i]; }
    }
    const float bias = bih[tid] + bhh[tid];

    const int start = starts[b];
    const int L = lens[b];

    if (tid < HDIM) {
        hbuf[tid] = 0.0f;
        if (L > 0) xbuf[0][tid] = x[(size_t)start * HDIM + tid];
    }
    __syncthreads();

    float c = 0.0f, h = 0.0f;   // valid in threads tid < HDIM (wave 0)

    for (int l = 0; l < L; ++l) {
        const int cur = l & 1;

        // Prefetch next x row (wave 0 lanes) while everyone does the matvec.
        float xnext = 0.0f;
        const bool pf = (tid < HDIM) && (l + 1 < L);
        if (pf) xnext = x[(size_t)(start + l + 1) * HDIM + tid];

        // g[tid] = bias + dot(Wih[tid,:], x_t) + dot(Whh[tid,:], h)
        const float4* xs = (const float4*)xbuf[cur];
        const float4* hs = (const float4*)hbuf;
        float g = bias;
#pragma unroll
        for (int k = 0; k < 16; ++k) {
            float4 xv = xs[k];   // broadcast LDS read (conflict-free)
            float4 hv = hs[k];
            float4 wi = wih[k];
            float4 wh = whh[k];
            g += wi.x * xv.x + wi.y * xv.y + wi.z * xv.z + wi.w * xv.w;
            g += wh.x * hv.x + wh.y * hv.y + wh.z * hv.z + wh.w * hv.w;
        }
        gbuf[tid] = g;
        if (pf) xbuf[cur ^ 1][tid] = xnext;
        __syncthreads();

        // Gate math + state update on wave 0 (element tid).
        if (tid < HDIM) {
            float gi = sigmoid_fast(gbuf[tid]);
            float gf = sigmoid_fast(gbuf[tid + HDIM]);
            float gc = tanh_fast(gbuf[tid + 2 * HDIM]);
            float go = sigmoid_fast(gbuf[tid + 3 * HDIM]);
            c = gf * c + gi * gc;
            h = go * tanh_fast(c);
            hbuf[tid] = h;
        }
        __syncthreads();
    }

    if (tid < HDIM) out[(size_t)b * HDIM + tid] = (L > 0) ? h : 0.0f;
}

extern "C" void kernel_launch(void* const* d_in, const int* in_sizes, int n_in,
                              void* d_out, int out_size, void* d_ws, size_t ws_size,
                              hipStream_t stream) {
    const float* x     = (const float*)d_in[0];
    const float* Wih   = (const float*)d_in[1];
    const float* Whh   = (const float*)d_in[2];
    const float* bih   = (const float*)d_in[3];
    const float* bhh   = (const float*)d_in[4];
    const int*   index = (const int*)d_in[5];

    const int N = in_sizes[5];
    const int B = out_size / HDIM;   // 8192

    int* starts = (int*)d_ws;
    int* lens   = starts + B;

    seg_bounds_kernel<<<(B + 255) / 256, 256, 0, stream>>>(index, N, B, starts, lens);
    lstm_kernel<<<B, 256, 0, stream>>>(x, Wih, Whh, bih, bhh, starts, lens,
                                       (float*)d_out);
}

// Round 2
// 340.925 us; speedup vs baseline: 2.9543x; 2.9543x over previous
//
#include <hip/hip_runtime.h>

#define MAXLEN 100
#define HDIM 64
#define HSTR 76   // bf16 elements per h-stage row (152 B: 8B-aligned, bank-spreading)

typedef __attribute__((ext_vector_type(8))) short bf16x8;
typedef __attribute__((ext_vector_type(4))) float f32x4;

// --- Kernel A: per-segment start offset + length via binary search (index sorted) ---
__global__ void seg_bounds_kernel(const int* __restrict__ index, int N, int B,
                                  int* __restrict__ starts, int* __restrict__ lens) {
    int b = blockIdx.x * blockDim.x + threadIdx.x;
    if (b >= B) return;
    int lo = 0, hi = N;
    while (lo < hi) { int mid = (lo + hi) >> 1; if (index[mid] < b) lo = mid + 1; else hi = mid; }
    int s = lo;
    hi = N;
    while (lo < hi) { int mid = (lo + hi) >> 1; if (index[mid] < b + 1) lo = mid + 1; else hi = mid; }
    int len = lo - s;
    starts[b] = s;
    lens[b] = len < MAXLEN ? len : MAXLEN;
}

__device__ __forceinline__ short f2bf(float f) {   // RNE float->bf16 (finite inputs)
    unsigned u = __float_as_uint(f);
    u += 0x7fffu + ((u >> 16) & 1u);
    return (short)(u >> 16);
}
__device__ __forceinline__ float fsig(float v) {
    float e = __expf(-v);
    return __fdividef(1.0f, 1.0f + e);
}
__device__ __forceinline__ float ftanh(float v) {
    float e = __expf(-2.0f * v);
    return __fdividef(2.0f, 1.0f + e) - 1.0f;
}

// --- Kernel B: 16 segments per block, 4 waves. Wave w owns hidden cols [w*16, w*16+16).
// Per step: g[s, g*64+n] = x_t[s,:]@Wih[row,:] + h[s,:]@Whh[row,:] + bias via 16 MFMAs.
// i/f/g/o for a (seg, hidden) pair live in the same lane+reg of the 4 accumulators ->
// gate math and c/h state are fully register-local. Only h crosses LDS (bf16, dbuf).
__global__ __launch_bounds__(256, 2)
void lstm_mfma_kernel(const float* __restrict__ x,
                      const float* __restrict__ Wih,
                      const float* __restrict__ Whh,
                      const float* __restrict__ bih,
                      const float* __restrict__ bhh,
                      const int* __restrict__ starts,
                      const int* __restrict__ lens,
                      float* __restrict__ out, int B) {
    const int tid  = threadIdx.x;
    const int w    = tid >> 6;        // wave id 0..3
    const int lane = tid & 63;
    const int l15  = lane & 15;
    const int quad = lane >> 4;
    const int segbase = blockIdx.x * 16;
    const int ncol = w * 16 + l15;    // hidden column this lane's B-frags cover

    __shared__ unsigned short hst[2][16][HSTR];   // h stage, bf16, double-buffered

    // Weight B-fragments (B[k][n] = W[gate*64+ncol, k]) + fused bias, in registers.
    bf16x8 wi[4][2], wh[4][2];
    f32x4 bias4[4];
#pragma unroll
    for (int g = 0; g < 4; ++g) {
        const int row = g * HDIM + ncol;          // gate row 0..255
        float bb = bih[row] + bhh[row];
        f32x4 b4 = {bb, bb, bb, bb};
        bias4[g] = b4;
#pragma unroll
        for (int kt = 0; kt < 2; ++kt) {
            const float* pi = Wih + (size_t)row * HDIM + kt * 32 + quad * 8;
            const float* ph = Whh + (size_t)row * HDIM + kt * 32 + quad * 8;
            bf16x8 ai, ah;
#pragma unroll
            for (int j = 0; j < 8; ++j) { ai[j] = f2bf(pi[j]); ah[j] = f2bf(ph[j]); }
            wi[g][kt] = ai; wh[g][kt] = ah;
        }
    }

    // Segment metadata.
    const int sf      = segbase + l15;
    const int start_f = (sf < B) ? starts[sf] : 0;
    const int len_f   = (sf < B) ? lens[sf]   : 0;
    int len4[4];
#pragma unroll
    for (int r = 0; r < 4; ++r) {
        int sg = segbase + quad * 4 + r;
        len4[r] = (sg < B) ? lens[sg] : 0;
    }

    // Block max length (reduce across the 16-lane segment group).
    int lmax = len_f;
#pragma unroll
    for (int d = 1; d < 16; d <<= 1) {
        int o = __shfl_xor(lmax, d);
        lmax = o > lmax ? o : lmax;
    }

    // Zero h stage (both buffers).
    for (int i = tid; i < 2 * 16 * HSTR; i += 256) ((unsigned short*)hst)[i] = 0;

    // Prefetch x row for t=0: lane holds x[seg=l15][kt*32+quad*8 .. +7].
    const float* xbase = x + (size_t)start_f * HDIM + quad * 8;
    f32x4 xq[2][2];
#pragma unroll
    for (int kt = 0; kt < 2; ++kt) {
        f32x4 v0 = {0, 0, 0, 0}, v1 = {0, 0, 0, 0};
        if (len_f > 0) {
            const f32x4* p = (const f32x4*)(xbase + kt * 32);
            v0 = p[0]; v1 = p[1];
        }
        xq[kt][0] = v0; xq[kt][1] = v1;
    }

    float c4[4] = {0, 0, 0, 0}, h4[4] = {0, 0, 0, 0};
    __syncthreads();

    for (int t = 0; t < lmax; ++t) {
        // Convert prefetched x to A-fragments.
        bf16x8 xa[2];
#pragma unroll
        for (int kt = 0; kt < 2; ++kt) {
            bf16x8 a;
#pragma unroll
            for (int j = 0; j < 4; ++j) { a[j] = f2bf(xq[kt][0][j]); a[j + 4] = f2bf(xq[kt][1][j]); }
            xa[kt] = a;
        }
        // Prefetch next x row (latency hidden behind MFMA + gate math).
        const bool pf = (t + 1 < len_f);
#pragma unroll
        for (int kt = 0; kt < 2; ++kt) {
            f32x4 v0 = xq[kt][0], v1 = xq[kt][1];
            if (pf) {
                const f32x4* p = (const f32x4*)(xbase + (size_t)(t + 1) * HDIM + kt * 32);
                v0 = p[0]; v1 = p[1];
            }
            xq[kt][0] = v0; xq[kt][1] = v1;
        }
        // h A-fragments from LDS (written last step, or zeros at t=0).
        bf16x8 ha[2];
#pragma unroll
        for (int kt = 0; kt < 2; ++kt) {
            const unsigned short* pp = &hst[t & 1][l15][kt * 32 + quad * 8];
            ushort4 u0 = *(const ushort4*)pp;
            ushort4 u1 = *(const ushort4*)(pp + 4);
            bf16x8 a;
            a[0] = (short)u0.x; a[1] = (short)u0.y; a[2] = (short)u0.z; a[3] = (short)u0.w;
            a[4] = (short)u1.x; a[5] = (short)u1.y; a[6] = (short)u1.z; a[7] = (short)u1.w;
            ha[kt] = a;
        }
        // 16 MFMAs: 4 gates x (2 K-tiles of x + 2 K-tiles of h), bias pre-loaded as C.
        f32x4 acc[4];
#pragma unroll
        for (int g = 0; g < 4; ++g) {
            f32x4 a = __builtin_amdgcn_mfma_f32_16x16x32_bf16(xa[0], wi[g][0], bias4[g], 0, 0, 0);
            a = __builtin_amdgcn_mfma_f32_16x16x32_bf16(xa[1], wi[g][1], a, 0, 0, 0);
            a = __builtin_amdgcn_mfma_f32_16x16x32_bf16(ha[0], wh[g][0], a, 0, 0, 0);
            a = __builtin_amdgcn_mfma_f32_16x16x32_bf16(ha[1], wh[g][1], a, 0, 0, 0);
            acc[g] = a;
        }
        // Gates + state update (register-local; C-layout row = segment quad*4+r).
#pragma unroll
        for (int r = 0; r < 4; ++r) {
            float gi = fsig(acc[0][r]);
            float gf = fsig(acc[1][r]);
            float gg = ftanh(acc[2][r]);
            float go = fsig(acc[3][r]);
            float cn = gf * c4[r] + gi * gg;
            float hn = go * ftanh(cn);
            if (t < len4[r]) { c4[r] = cn; h4[r] = hn; }   // freeze past end-of-seq
            hst[(t + 1) & 1][quad * 4 + r][ncol] = (unsigned short)f2bf(h4[r]);
        }
        __syncthreads();
    }

    // Final hidden state (zero-length segments stay 0).
#pragma unroll
    for (int r = 0; r < 4; ++r) {
        const int seg = segbase + quad * 4 + r;
        if (seg < B) out[(size_t)seg * HDIM + ncol] = h4[r];
    }
}

extern "C" void kernel_launch(void* const* d_in, const int* in_sizes, int n_in,
                              void* d_out, int out_size, void* d_ws, size_t ws_size,
                              hipStream_t stream) {
    const float* x     = (const float*)d_in[0];
    const float* Wih   = (const float*)d_in[1];
    const float* Whh   = (const float*)d_in[2];
    const float* bih   = (const float*)d_in[3];
    const float* bhh   = (const float*)d_in[4];
    const int*   index = (const int*)d_in[5];

    const int N = in_sizes[5];
    const int B = out_size / HDIM;   // 8192

    int* starts = (int*)d_ws;
    int* lens   = starts + B;

    seg_bounds_kernel<<<(B + 255) / 256, 256, 0, stream>>>(index, N, B, starts, lens);

    const int nblocks = (B + 15) / 16;
    lstm_mfma_kernel<<<nblocks, 256, 0, stream>>>(x, Wih, Whh, bih, bhh,
                                                  starts, lens, (float*)d_out, B);
}